// Round 7
// baseline (36298.505 us; speedup 1.0000x reference)
//
#include <hip/hip_runtime.h>

#define T_N 512
#define B_N 32
#define H_N 512
#define G3 1536
#define NBLK 192
#define NGRP 16
#define GRPSZ (NBLK / NGRP)     // 12
#define NT 1024
#define EPS_LN 1e-5f
#define OUT_HID_OFF (T_N * B_N * 1024)

// ws layout (floats):
//  [0..640)     barrier: 16 group counters (32-uint spacing) + top(512) + rel(544)
//  [640)        stats ring: 2 parity x (4 kd x 3 g x 32 b x 2) = 2 x 768
//  [2176)       dots: 4 kd x 32 b x 1536 j
//  [198784)     hbuf: 2 d x 32 b x 512
//  [231552)     y0: 2 d x 512 t x 32 b x 512  (cstore ph0, plain-read ph1)
#define WS_STATS 640
#define WS_DOTS  (WS_STATS + 1536)
#define WS_HBUF  (WS_DOTS + 4 * B_N * G3)
#define WS_Y0    (WS_HBUF + 2 * B_N * H_N)

// LDS (dynamic, 163072 B — baseline-proven size):
//  wlds: 126 k4 x 64 j x 4  = 32256 floats (k = 0..503)
//  hl:   16 b x 516         =  8256 floats (k-padded h tile)
//  sred: 256 floats ([b_loc 16][jq 2][st 2] used)
#define WLDS_F 32256
#define HL_F   8256
#define LDS_BYTES ((WLDS_F + HL_F + 256) * 4)

__device__ __forceinline__ float cload(const float* p) {
  return __hip_atomic_load(p, __ATOMIC_RELAXED, __HIP_MEMORY_SCOPE_AGENT);
}
__device__ __forceinline__ void cstore(float* p, float v) {
  __hip_atomic_store(p, v, __ATOMIC_RELAXED, __HIP_MEMORY_SCOPE_AGENT);
}
union U64F2 { unsigned long long u; float f[2]; };
__device__ __forceinline__ U64F2 cload2(const float* p) {
  U64F2 r;
  r.u = __hip_atomic_load((const unsigned long long*)p, __ATOMIC_RELAXED,
                          __HIP_MEMORY_SCOPE_AGENT);
  return r;
}

// Hierarchical fence-free grid barrier: 12-way arrive on 16 lines, 16-way top.
__device__ __forceinline__ void gbar(unsigned* barbase, unsigned& epoch, int grp) {
  epoch++;
  __builtin_amdgcn_s_waitcnt(0);   // drain my vmem: coherent stores at L3
  __syncthreads();
  if (threadIdx.x == 0) {
    unsigned* gc  = barbase + grp * 32;
    unsigned* top = barbase + 512;
    unsigned* rel = barbase + 544;
    unsigned r = __hip_atomic_fetch_add(gc, 1u, __ATOMIC_RELAXED, __HIP_MEMORY_SCOPE_AGENT);
    if (r == epoch * GRPSZ - 1u) {
      unsigned r2 = __hip_atomic_fetch_add(top, 1u, __ATOMIC_RELAXED, __HIP_MEMORY_SCOPE_AGENT);
      if (r2 == epoch * NGRP - 1u)
        __hip_atomic_store(rel, epoch, __ATOMIC_RELAXED, __HIP_MEMORY_SCOPE_AGENT);
    }
    while (__hip_atomic_load(rel, __ATOMIC_RELAXED, __HIP_MEMORY_SCOPE_AGENT) < epoch)
      __builtin_amdgcn_s_sleep(1);
  }
  __syncthreads();
}

// 8 FMAs: one j-column weight W against 2 b-rows (R1,R2), componentwise.
#define FMA_M(M, W, R1, R2) do { \
  acc[M][0][0]=fmaf((R1).x,(W).x,acc[M][0][0]); acc[M][0][1]=fmaf((R1).y,(W).y,acc[M][0][1]); \
  acc[M][0][2]=fmaf((R1).z,(W).z,acc[M][0][2]); acc[M][0][3]=fmaf((R1).w,(W).w,acc[M][0][3]); \
  acc[M][1][0]=fmaf((R2).x,(W).x,acc[M][1][0]); acc[M][1][1]=fmaf((R2).y,(W).y,acc[M][1][1]); \
  acc[M][1][2]=fmaf((R2).z,(W).z,acc[M][1][2]); acc[M][1][3]=fmaf((R2).w,(W).w,acc[M][1][3]); \
} while (0)

__global__ void __launch_bounds__(NT, 1)
lngru12(const float* __restrict__ x, const float* __restrict__ h0,
        const float* __restrict__ Wx, const float* __restrict__ Wh,
        const float* __restrict__ bx, const float* __restrict__ bh,
        const float* __restrict__ gx, const float* __restrict__ bex,
        const float* __restrict__ gh, const float* __restrict__ beh,
        float* __restrict__ out, float* __restrict__ ws)
{
  extern __shared__ __align__(16) float smem[];
  float* wlds = smem;                    // [k4 126][j 64][4]
  float* hl   = smem + WLDS_F;           // [b 16][516]
  float* sred = smem + WLDS_F + HL_F;    // [b_loc 16][jq 2][st 2]

  unsigned* barbase = (unsigned*)ws;
  float* stats = ws + WS_STATS;
  float* dots  = ws + WS_DOTS;
  float* hbuf  = ws + WS_HBUF;
  float* y0    = ws + WS_Y0;

  const int tid  = threadIdx.x;
  const int lane = tid & 63;
  const int wv   = tid >> 6;              // 16 waves
  const int bid  = blockIdx.x;
  const int grp  = bid & 15;
  const int bs   = bid & 1;               // b-half
  const int jt   = (bid >> 1) % 24;       // 64-wide j tile
  const int kd   = (bid >> 1) / 24;       // d*2 + kind
  const int kind = kd & 1;                // 0: ax, 1: ah
  const int d    = kd >> 1;
  const int j0   = jt * 64;
  const int g    = jt >> 3;               // gate of this j-tile
  const int b0   = bs * 16;
  const bool is_gate = (kind == 0) && (jt < 8);

  // GEMM: 2 waves (wv<2); lane = (boct 8)x(jj 8); lane tile 4j x 2b:
  //   j_local = jq*32 + m*8 + jj (m=0..3), b_local = boct, boct+8. Full K.
  const bool gw  = (wv < 2);
  const int jq   = wv & 1;
  const int jj   = lane & 7;
  const int boct = lane >> 3;

  unsigned epoch = 0;

  for (int ph = 0; ph < 2; ++ph) {
    const int widx = ph * 2 + d;

    // ---- stage weights: k<504 -> LDS, k>=504 -> gw-lane tail regs ----
    const float* wgl = (kind ? Wh : Wx) + (size_t)widx * H_N * G3 + j0;
    for (int kk = 0; kk < 32; ++kk) {
      int k = wv * 32 + kk;
      if (k < 504)
        wlds[(k >> 2) * 256 + lane * 4 + (k & 3)] = wgl[(size_t)k * G3 + lane];
    }
    float4 wt[4][2];
    float  bva[4];
    if (gw) {
#pragma unroll
      for (int m = 0; m < 4; ++m) {
        const int jl = jq * 32 + m * 8 + jj;
        bva[m] = (kind ? bh : bx)[widx * G3 + j0 + jl];
#pragma unroll
        for (int h = 0; h < 2; ++h) {
          wt[m][h].x = wgl[(size_t)(504 + 4*h + 0) * G3 + jl];
          wt[m][h].y = wgl[(size_t)(504 + 4*h + 1) * G3 + jl];
          wt[m][h].z = wgl[(size_t)(504 + 4*h + 2) * G3 + jl];
          wt[m][h].w = wgl[(size_t)(504 + 4*h + 3) * G3 + jl];
        }
      }
    }

    if (is_gate) {
      cstore(&hbuf[(d * B_N + b0 + wv) * H_N + j0 + lane],
             h0[((size_t)widx * B_N + b0 + wv) * H_N + j0 + lane]);
    }
    gbar(barbase, epoch, grp);

    const float* xsrc = (ph == 0) ? x : (y0 + (size_t)d * T_N * B_N * H_N);
    const float* hsrc = hbuf + (d * B_N + b0) * H_N;   // 16 b x 512, contiguous
    const float4* wbase = (const float4*)wlds + jq * 32 + jj;

    for (int s = 0; s < T_N; ++s) {
      const int t = d ? (T_N - 1 - s) : s;
      const int p = s & 1;
      float* stp = stats + p * 768;

      // ---- kind=1: stage h(t-1) tile into LDS (coalesced coherent) ----
      if (kind) {
#pragma unroll
        for (int q = 0; q < 4; ++q) {
          int e = (tid + q * 1024) * 2;       // element 0..8190, even
          U64F2 v = cload2(hsrc + e);
          int bb = e >> 9, k = e & 511;
          hl[bb * 516 + k]     = v.f[0];
          hl[bb * 516 + k + 1] = v.f[1];
        }
        __syncthreads();
      }

      // ---- GEMM: 2 waves, lane computes 4j x 2b over full K=512 ----
      float acc[4][2][4] = {};
      if (gw) {
        if (kind) {
          const float* h1 = hl + boct * 516;
          const float* h2 = h1 + 8 * 516;
#pragma unroll 3
          for (int k4 = 0; k4 < 126; ++k4) {
            float4 w0 = wbase[k4*64 + 0];
            float4 w1 = wbase[k4*64 + 8];
            float4 w2 = wbase[k4*64 + 16];
            float4 w3 = wbase[k4*64 + 24];
            float4 r1 = *(const float4*)(h1 + k4*4);
            float4 r2 = *(const float4*)(h2 + k4*4);
            FMA_M(0,w0,r1,r2); FMA_M(1,w1,r1,r2);
            FMA_M(2,w2,r1,r2); FMA_M(3,w3,r1,r2);
          }
          float4 r1a = *(const float4*)(h1 + 504);
          float4 r1b = *(const float4*)(h1 + 508);
          float4 r2a = *(const float4*)(h2 + 504);
          float4 r2b = *(const float4*)(h2 + 508);
          FMA_M(0,wt[0][0],r1a,r2a); FMA_M(1,wt[1][0],r1a,r2a);
          FMA_M(2,wt[2][0],r1a,r2a); FMA_M(3,wt[3][0],r1a,r2a);
          FMA_M(0,wt[0][1],r1b,r2b); FMA_M(1,wt[1][1],r1b,r2b);
          FMA_M(2,wt[2][1],r1b,r2b); FMA_M(3,wt[3][1],r1b,r2b);
        } else {
          const float* rp1 = xsrc + ((size_t)t * B_N + b0 + boct) * H_N;
          const float* rp2 = rp1 + 8 * H_N;
#pragma unroll 4
          for (int k4 = 0; k4 < 126; ++k4) {
            float4 w0 = wbase[k4*64 + 0];
            float4 w1 = wbase[k4*64 + 8];
            float4 w2 = wbase[k4*64 + 16];
            float4 w3 = wbase[k4*64 + 24];
            float4 r1 = *(const float4*)(rp1 + k4*4);
            float4 r2 = *(const float4*)(rp2 + k4*4);
            FMA_M(0,w0,r1,r2); FMA_M(1,w1,r1,r2);
            FMA_M(2,w2,r1,r2); FMA_M(3,w3,r1,r2);
          }
          float4 r1a = *(const float4*)(rp1 + 504);
          float4 r1b = *(const float4*)(rp1 + 508);
          float4 r2a = *(const float4*)(rp2 + 504);
          float4 r2b = *(const float4*)(rp2 + 508);
          FMA_M(0,wt[0][0],r1a,r2a); FMA_M(1,wt[1][0],r1a,r2a);
          FMA_M(2,wt[2][0],r1a,r2a); FMA_M(3,wt[3][0],r1a,r2a);
          FMA_M(0,wt[0][1],r1b,r2b); FMA_M(1,wt[1][1],r1b,r2b);
          FMA_M(2,wt[2][1],r1b,r2b); FMA_M(3,wt[3][1],r1b,r2b);
        }

        // ---- dots store + LN stats ----
        float* dr1 = &dots[(size_t)(kd * B_N + b0 + boct) * G3 + j0];
        float* dr2 = dr1 + (size_t)8 * G3;
        float s1a = 0.f, s2a = 0.f, s1b = 0.f, s2b = 0.f;
#pragma unroll
        for (int m = 0; m < 4; ++m) {
          const int jl = jq * 32 + m * 8 + jj;
          float t1 = bva[m] + ((acc[m][0][0]+acc[m][0][1]) + (acc[m][0][2]+acc[m][0][3]));
          float t2 = bva[m] + ((acc[m][1][0]+acc[m][1][1]) + (acc[m][1][2]+acc[m][1][3]));
          cstore(dr1 + jl, t1);
          cstore(dr2 + jl, t2);
          s1a += t1; s2a += t1 * t1; s1b += t2; s2b += t2 * t2;
        }
        s1a += __shfl_xor(s1a, 1, 64); s2a += __shfl_xor(s2a, 1, 64);
        s1b += __shfl_xor(s1b, 1, 64); s2b += __shfl_xor(s2b, 1, 64);
        s1a += __shfl_xor(s1a, 2, 64); s2a += __shfl_xor(s2a, 2, 64);
        s1b += __shfl_xor(s1b, 2, 64); s2b += __shfl_xor(s2b, 2, 64);
        s1a += __shfl_xor(s1a, 4, 64); s2a += __shfl_xor(s2a, 4, 64);
        s1b += __shfl_xor(s1b, 4, 64); s2b += __shfl_xor(s2b, 4, 64);
        if (jj == 0) {
          sred[boct * 4 + jq * 2 + 0] = s1a;
          sred[boct * 4 + jq * 2 + 1] = s2a;
          sred[(boct + 8) * 4 + jq * 2 + 0] = s1b;
          sred[(boct + 8) * 4 + jq * 2 + 1] = s2b;
        }
      }
      __syncthreads();
      if (tid < 32) {
        int bl = tid >> 1, st = tid & 1;
        float a2 = sred[bl * 4 + st] + sred[bl * 4 + 2 + st];
        atomicAdd(&stp[((kd * 3 + g) * B_N + b0 + bl) * 2 + st], a2);
      }

      gbar(barbase, epoch, grp);  // B1: dots + stats visible

      // ---- gates + h update ----
      if (bid == NBLK - 1) {
        float* so = stats + (p ^ 1) * 768;
        if (tid < 768) cstore(so + tid, 0.f);
      }
      if (is_gate) {
        const int c  = j0 + lane;
        const int gb = b0 + wv;
        float a[2][3];
#pragma unroll
        for (int k2 = 0; k2 < 2; ++k2) {
          const float* dr  = dots + ((d * 2 + k2) * B_N + gb) * G3;
          const float* gam = (k2 ? gh : gx) + widx * G3;
          const float* bet = (k2 ? beh : bex) + widx * G3;
#pragma unroll
          for (int g2 = 0; g2 < 3; ++g2) {
            float v = cload(dr + g2 * H_N + c);
            const float* sl = stp + (((d * 2 + k2) * 3 + g2) * B_N + gb) * 2;
            float mu  = cload(sl)     * (1.f / 512.f);
            float var = cload(sl + 1) * (1.f / 512.f) - mu * mu;
            float inv = rsqrtf(var + EPS_LN);
            int J = g2 * H_N + c;
            a[k2][g2] = (v - mu) * inv * gam[J] + bet[J];
          }
        }
        float r = 1.f / (1.f + __expf(-(a[0][0] + a[1][0])));
        float z = 1.f / (1.f + __expf(-(a[0][1] + a[1][1])));
        float n = tanhf(a[0][2] + r * a[1][2]);
        float* hp = hbuf + (d * B_N + gb) * H_N + c;
        float hnew = (1.f - z) * n + z * cload(hp);
        cstore(hp, hnew);
        if (ph == 0) {
          cstore(&y0[(((size_t)d * T_N + t) * B_N + gb) * H_N + c], hnew);
        } else {
          out[((size_t)t * B_N + gb) * 1024 + d * H_N + c] = hnew;
        }
        if (s == T_N - 1) {
          out[OUT_HID_OFF + ((size_t)widx * B_N + gb) * H_N + c] = hnew;
        }
      }
      gbar(barbase, epoch, grp);  // B2: h(t) visible
    }
  }
}

extern "C" void kernel_launch(void* const* d_in, const int* in_sizes, int n_in,
                              void* d_out, int out_size, void* d_ws, size_t ws_size,
                              hipStream_t stream) {
  const float* x    = (const float*)d_in[0];
  const float* h0   = (const float*)d_in[1];
  const float* Wx   = (const float*)d_in[2];
  const float* Wh   = (const float*)d_in[3];
  const float* bxp  = (const float*)d_in[4];
  const float* bhp  = (const float*)d_in[5];
  const float* gxp  = (const float*)d_in[6];
  const float* bexp = (const float*)d_in[7];
  const float* ghp  = (const float*)d_in[8];
  const float* behp = (const float*)d_in[9];
  float* out = (float*)d_out;
  float* ws  = (float*)d_ws;

  hipMemsetAsync(d_ws, 0, 12288, stream);   // barrier lines + stats ring

  hipFuncSetAttribute((const void*)lngru12,
                      hipFuncAttributeMaxDynamicSharedMemorySize, LDS_BYTES);

  void* args[] = {(void*)&x, (void*)&h0, (void*)&Wx, (void*)&Wh, (void*)&bxp, (void*)&bhp,
                  (void*)&gxp, (void*)&bexp, (void*)&ghp, (void*)&behp, (void*)&out, (void*)&ws};
  hipLaunchCooperativeKernel((void*)lngru12, dim3(NBLK), dim3(NT), args, LDS_BYTES, stream);
}

// Round 8
// 21389.832 us; speedup vs baseline: 1.6970x; 1.6970x over previous
//
#include <hip/hip_runtime.h>

#define T_N 512
#define B_N 32
#define H_N 512
#define G3 1536
#define NBLK 192
#define NT 1024
#define EPS_LN 1e-5f
#define OUT_HID_OFF (T_N * B_N * 1024)
#define COLL_BID 16   // kind0, jt=8 (non-gate): idle in gate window

// ws layout (floats):
//  [0..192)     arrive flags: 1 uint per block (monotone epoch)
//  [256]        release word (monotone epoch)
//  [448]        stats ring: 2 parity x (4 kd x 3 g x 32 b x 2) = 2 x 768
//  [1984]       dots: 4 kd x 32 b x 1536 j
//  [198592]     hbuf: 2 d x 32 b x 512
//  [231360]     y0: 2 d x 512 t x 32 b x 512  (cstore ph0, plain-read ph1)
#define WS_STATS 448
#define WS_DOTS  (WS_STATS + 1536)
#define WS_HBUF  (WS_DOTS + 4 * B_N * G3)
#define WS_Y0    (WS_HBUF + 2 * B_N * H_N)

// LDS (dynamic, 163072 B total — baseline-proven size):
//  wlds: 126 k4 x 64 j x 4  = 32256 floats (k = 0..503)
//  hl:   16 b x 516         =  8256 floats (k-padded h tile)
//  sred: 256 floats ([b_loc 16][jq 4][2] used)
#define WLDS_F 32256
#define HL_F   8256
#define LDS_BYTES ((WLDS_F + HL_F + 256) * 4)

__device__ __forceinline__ float cload(const float* p) {
  return __hip_atomic_load(p, __ATOMIC_RELAXED, __HIP_MEMORY_SCOPE_AGENT);
}
__device__ __forceinline__ void cstore(float* p, float v) {
  __hip_atomic_store(p, v, __ATOMIC_RELAXED, __HIP_MEMORY_SCOPE_AGENT);
}
union U64F2 { unsigned long long u; float f[2]; };
__device__ __forceinline__ U64F2 cload2(const float* p) {
  U64F2 r;
  r.u = __hip_atomic_load((const unsigned long long*)p, __ATOMIC_RELAXED,
                          __HIP_MEMORY_SCOPE_AGENT);
  return r;
}

// Flag-based grid barrier: per-block arrive flag (plain store, no RMW
// contention), collector block polls all flags with 192 threads, single
// release word. Monotone epochs — no flag reset needed.
__device__ __forceinline__ void gbar(unsigned* barbase, unsigned& epoch, int bid) {
  epoch++;
  unsigned* arr = barbase;
  unsigned* rel = barbase + 256;
  __builtin_amdgcn_s_waitcnt(0);   // drain my vmem: coherent stores at L3
  __syncthreads();
  const int tid = threadIdx.x;
  if (tid == 0)
    __hip_atomic_store(&arr[bid], epoch, __ATOMIC_RELAXED, __HIP_MEMORY_SCOPE_AGENT);
  if (bid == COLL_BID) {
    if (tid < NBLK) {
      while (__hip_atomic_load(&arr[tid], __ATOMIC_RELAXED, __HIP_MEMORY_SCOPE_AGENT) < epoch)
        __builtin_amdgcn_s_sleep(1);
    }
    __syncthreads();
    if (tid == 0)
      __hip_atomic_store(rel, epoch, __ATOMIC_RELAXED, __HIP_MEMORY_SCOPE_AGENT);
  } else {
    if (tid == 0) {
      while (__hip_atomic_load(rel, __ATOMIC_RELAXED, __HIP_MEMORY_SCOPE_AGENT) < epoch)
        __builtin_amdgcn_s_sleep(1);
    }
  }
  __syncthreads();
}

// 16 FMAs: 2 j-weights (WA,WB) x 2 b-rows (R1,R2), componentwise (c = k&3).
#define FMA16(WA, WB, R1, R2) do { \
  acc[0][0][0]=fmaf((R1).x,(WA).x,acc[0][0][0]); acc[0][0][1]=fmaf((R1).y,(WA).y,acc[0][0][1]); \
  acc[0][0][2]=fmaf((R1).z,(WA).z,acc[0][0][2]); acc[0][0][3]=fmaf((R1).w,(WA).w,acc[0][0][3]); \
  acc[0][1][0]=fmaf((R2).x,(WA).x,acc[0][1][0]); acc[0][1][1]=fmaf((R2).y,(WA).y,acc[0][1][1]); \
  acc[0][1][2]=fmaf((R2).z,(WA).z,acc[0][1][2]); acc[0][1][3]=fmaf((R2).w,(WA).w,acc[0][1][3]); \
  acc[1][0][0]=fmaf((R1).x,(WB).x,acc[1][0][0]); acc[1][0][1]=fmaf((R1).y,(WB).y,acc[1][0][1]); \
  acc[1][0][2]=fmaf((R1).z,(WB).z,acc[1][0][2]); acc[1][0][3]=fmaf((R1).w,(WB).w,acc[1][0][3]); \
  acc[1][1][0]=fmaf((R2).x,(WB).x,acc[1][1][0]); acc[1][1][1]=fmaf((R2).y,(WB).y,acc[1][1][1]); \
  acc[1][1][2]=fmaf((R2).z,(WB).z,acc[1][1][2]); acc[1][1][3]=fmaf((R2).w,(WB).w,acc[1][1][3]); \
} while (0)

__global__ void __launch_bounds__(NT, 1)
lngru13(const float* __restrict__ x, const float* __restrict__ h0,
        const float* __restrict__ Wx, const float* __restrict__ Wh,
        const float* __restrict__ bx, const float* __restrict__ bh,
        const float* __restrict__ gx, const float* __restrict__ bex,
        const float* __restrict__ gh, const float* __restrict__ beh,
        float* __restrict__ out, float* __restrict__ ws)
{
  extern __shared__ __align__(16) float smem[];
  float* wlds = smem;                    // [k4 126][j 64][4]
  float* hl   = smem + WLDS_F;           // [b 16][516]
  float* sred = smem + WLDS_F + HL_F;    // [b_loc 16][jq 4][2]

  unsigned* barbase = (unsigned*)ws;
  float* stats = ws + WS_STATS;
  float* dots  = ws + WS_DOTS;
  float* hbuf  = ws + WS_HBUF;
  float* y0    = ws + WS_Y0;

  const int tid  = threadIdx.x;
  const int lane = tid & 63;
  const int wv   = tid >> 6;              // 16 waves
  const int bid  = blockIdx.x;
  const int bs   = bid & 1;               // b-half
  const int jt   = (bid >> 1) % 24;       // 64-wide j tile
  const int kd   = (bid >> 1) / 24;       // d*2 + kind
  const int kind = kd & 1;                // 0: ax, 1: ah
  const int d    = kd >> 1;
  const int j0   = jt * 64;
  const int g    = jt >> 3;               // gate of this j-tile
  const int b0   = bs * 16;
  const bool is_gate = (kind == 0) && (jt < 8);

  // GEMM decomposition: 4 GEMM waves (wv<4); lane = (boct 8)x(jj 8);
  // lane tile = 2j x 2b: j in {j0+jq*8+jj, +32}, b in {b0+boct, +8}, full K.
  const bool gw  = (wv < 4);
  const int jq   = wv & 3;                // safe for all wv (index range)
  const int jj   = lane & 7;
  const int boct = lane >> 3;
  const int jla  = jq * 8 + jj;           // local j of first column
  const int jlb  = jla + 32;

  unsigned epoch = 0;

  for (int ph = 0; ph < 2; ++ph) {
    const int widx = ph * 2 + d;

    // ---- stage weights: k<504 -> LDS, k>=504 -> per-lane tail regs ----
    const float* wgl = (kind ? Wh : Wx) + (size_t)widx * H_N * G3 + j0;
    for (int kk = 0; kk < 32; ++kk) {
      int k = wv * 32 + kk;
      if (k < 504)
        wlds[(k >> 2) * 256 + lane * 4 + (k & 3)] = wgl[(size_t)k * G3 + lane];
    }
    float4 wt[2][2];                      // [ji][h]: k = 504+4h+c, j = jla/jlb
    if (gw) {
#pragma unroll
      for (int h = 0; h < 2; ++h) {
        wt[0][h].x = wgl[(size_t)(504 + 4*h + 0) * G3 + jla];
        wt[0][h].y = wgl[(size_t)(504 + 4*h + 1) * G3 + jla];
        wt[0][h].z = wgl[(size_t)(504 + 4*h + 2) * G3 + jla];
        wt[0][h].w = wgl[(size_t)(504 + 4*h + 3) * G3 + jla];
        wt[1][h].x = wgl[(size_t)(504 + 4*h + 0) * G3 + jlb];
        wt[1][h].y = wgl[(size_t)(504 + 4*h + 1) * G3 + jlb];
        wt[1][h].z = wgl[(size_t)(504 + 4*h + 2) * G3 + jlb];
        wt[1][h].w = wgl[(size_t)(504 + 4*h + 3) * G3 + jlb];
      }
    }

    if (is_gate) {
      cstore(&hbuf[(d * B_N + b0 + wv) * H_N + j0 + lane],
             h0[(widx * B_N + b0 + wv) * H_N + j0 + lane]);
    }
    gbar(barbase, epoch, bid);

    const float  bva  = (kind ? bh : bx)[widx * G3 + j0 + jla];
    const float  bvb  = (kind ? bh : bx)[widx * G3 + j0 + jlb];
    const float* xsrc = (ph == 0) ? x : (y0 + (size_t)d * T_N * B_N * H_N);
    const float* hsrc = hbuf + (d * B_N + b0) * H_N;   // 16 b x 512, contiguous
    const float4* wqa = (const float4*)wlds + jla;
    const float4* wqb = (const float4*)wlds + jlb;
    const float*  h1  = hl + boct * 516;
    const float*  h2  = hl + (boct + 8) * 516;

    for (int s = 0; s < T_N; ++s) {
      const int t = d ? (T_N - 1 - s) : s;
      const int p = s & 1;
      float* stp = stats + p * 768;

      // ---- kind=1: stage h(t-1) tile into LDS (coalesced coherent) ----
      if (kind) {
#pragma unroll
        for (int q = 0; q < 4; ++q) {
          int e = (tid + q * 1024) * 2;       // element 0..8190, even
          U64F2 v = cload2(hsrc + e);
          int bb = e >> 9, k = e & 511;
          hl[bb * 516 + k]     = v.f[0];
          hl[bb * 516 + k + 1] = v.f[1];
        }
        __syncthreads();
      }

      // ---- GEMM: lane computes 2j x 2b over full K=512 (waves 0..3) ----
      float acc[2][2][4] = {{{0.f,0.f,0.f,0.f},{0.f,0.f,0.f,0.f}},
                            {{0.f,0.f,0.f,0.f},{0.f,0.f,0.f,0.f}}};
      if (gw) {
        if (kind) {
#pragma unroll 3
          for (int k4 = 0; k4 < 126; ++k4) {
            float4 wa = wqa[k4 * 64];
            float4 wb = wqb[k4 * 64];
            float4 r1 = *(const float4*)(h1 + k4 * 4);
            float4 r2 = *(const float4*)(h2 + k4 * 4);
            FMA16(wa, wb, r1, r2);
          }
          {
            float4 r1a = *(const float4*)(h1 + 504);
            float4 r1b = *(const float4*)(h1 + 508);
            float4 r2a = *(const float4*)(h2 + 504);
            float4 r2b = *(const float4*)(h2 + 508);
            FMA16(wt[0][0], wt[1][0], r1a, r2a);
            FMA16(wt[0][1], wt[1][1], r1b, r2b);
          }
        } else {
          const float* rp1 = xsrc + ((size_t)t * B_N + b0 + boct) * H_N;
          const float* rp2 = rp1 + 8 * H_N;
#pragma unroll 6
          for (int k4 = 0; k4 < 126; ++k4) {
            float4 wa = wqa[k4 * 64];
            float4 wb = wqb[k4 * 64];
            float4 r1 = *(const float4*)(rp1 + k4 * 4);
            float4 r2 = *(const float4*)(rp2 + k4 * 4);
            FMA16(wa, wb, r1, r2);
          }
          {
            float4 r1a = *(const float4*)(rp1 + 504);
            float4 r1b = *(const float4*)(rp1 + 508);
            float4 r2a = *(const float4*)(rp2 + 504);
            float4 r2b = *(const float4*)(rp2 + 508);
            FMA16(wt[0][0], wt[1][0], r1a, r2a);
            FMA16(wt[0][1], wt[1][1], r1b, r2b);
          }
        }
      }

      // ---- dots store + LN stats (GEMM waves only) ----
      if (gw) {
        float ta1 = bva + (acc[0][0][0] + acc[0][0][1]) + (acc[0][0][2] + acc[0][0][3]);
        float ta2 = bva + (acc[0][1][0] + acc[0][1][1]) + (acc[0][1][2] + acc[0][1][3]);
        float tb1 = bvb + (acc[1][0][0] + acc[1][0][1]) + (acc[1][0][2] + acc[1][0][3]);
        float tb2 = bvb + (acc[1][1][0] + acc[1][1][1]) + (acc[1][1][2] + acc[1][1][3]);

        float* dr1 = &dots[(size_t)(kd * B_N + b0 + boct) * G3 + j0];
        float* dr2 = dr1 + (size_t)8 * G3;
        cstore(dr1 + jla, ta1);
        cstore(dr1 + jlb, tb1);
        cstore(dr2 + jla, ta2);
        cstore(dr2 + jlb, tb2);

        float s1a = ta1 + tb1, s2a = ta1 * ta1 + tb1 * tb1;   // b = b0+boct
        float s1b = ta2 + tb2, s2b = ta2 * ta2 + tb2 * tb2;   // b = b0+boct+8
        s1a += __shfl_xor(s1a, 1, 64); s2a += __shfl_xor(s2a, 1, 64);
        s1b += __shfl_xor(s1b, 1, 64); s2b += __shfl_xor(s2b, 1, 64);
        s1a += __shfl_xor(s1a, 2, 64); s2a += __shfl_xor(s2a, 2, 64);
        s1b += __shfl_xor(s1b, 2, 64); s2b += __shfl_xor(s2b, 2, 64);
        s1a += __shfl_xor(s1a, 4, 64); s2a += __shfl_xor(s2a, 4, 64);
        s1b += __shfl_xor(s1b, 4, 64); s2b += __shfl_xor(s2b, 4, 64);
        if (jj == 0) {
          sred[(boct * 4 + jq) * 2 + 0] = s1a;
          sred[(boct * 4 + jq) * 2 + 1] = s2a;
          sred[((boct + 8) * 4 + jq) * 2 + 0] = s1b;
          sred[((boct + 8) * 4 + jq) * 2 + 1] = s2b;
        }
      }
      __syncthreads();
      if (tid < 32) {
        int bl = tid >> 1, st = tid & 1;
        float a2 = 0.f;
#pragma unroll
        for (int q = 0; q < 4; ++q) a2 += sred[(bl * 4 + q) * 2 + st];
        atomicAdd(&stp[((kd * 3 + g) * B_N + b0 + bl) * 2 + st], a2);
      }

      gbar(barbase, epoch, bid);  // B1: dots + stats visible

      // ---- gates + h update ----
      if (bid == NBLK - 1) {
        float* so = stats + (p ^ 1) * 768;
        if (tid < 768) cstore(so + tid, 0.f);
      }
      if (is_gate) {
        const int c  = j0 + lane;
        const int gb = b0 + wv;
        float a[2][3];
#pragma unroll
        for (int k2 = 0; k2 < 2; ++k2) {
          const float* dr  = dots + ((d * 2 + k2) * B_N + gb) * G3;
          const float* gam = (k2 ? gh : gx) + widx * G3;
          const float* bet = (k2 ? beh : bex) + widx * G3;
#pragma unroll
          for (int g2 = 0; g2 < 3; ++g2) {
            float v = cload(dr + g2 * H_N + c);
            const float* sl = stp + (((d * 2 + k2) * 3 + g2) * B_N + gb) * 2;
            float mu  = cload(sl)     * (1.f / 512.f);
            float var = cload(sl + 1) * (1.f / 512.f) - mu * mu;
            float inv = rsqrtf(var + EPS_LN);
            int J = g2 * H_N + c;
            a[k2][g2] = (v - mu) * inv * gam[J] + bet[J];
          }
        }
        float r = 1.f / (1.f + __expf(-(a[0][0] + a[1][0])));
        float z = 1.f / (1.f + __expf(-(a[0][1] + a[1][1])));
        float n = tanhf(a[0][2] + r * a[1][2]);
        float* hp = hbuf + (d * B_N + gb) * H_N + c;
        float hnew = (1.f - z) * n + z * cload(hp);
        cstore(hp, hnew);
        if (ph == 0) {
          cstore(&y0[(((size_t)d * T_N + t) * B_N + gb) * H_N + c], hnew);
        } else {
          out[((size_t)t * B_N + gb) * 1024 + d * H_N + c] = hnew;
        }
        if (s == T_N - 1) {
          out[OUT_HID_OFF + (widx * B_N + gb) * H_N + c] = hnew;
        }
      }
      gbar(barbase, epoch, bid);  // B2: h(t) visible
    }
  }
}

extern "C" void kernel_launch(void* const* d_in, const int* in_sizes, int n_in,
                              void* d_out, int out_size, void* d_ws, size_t ws_size,
                              hipStream_t stream) {
  const float* x    = (const float*)d_in[0];
  const float* h0   = (const float*)d_in[1];
  const float* Wx   = (const float*)d_in[2];
  const float* Wh   = (const float*)d_in[3];
  const float* bxp  = (const float*)d_in[4];
  const float* bhp  = (const float*)d_in[5];
  const float* gxp  = (const float*)d_in[6];
  const float* bexp = (const float*)d_in[7];
  const float* ghp  = (const float*)d_in[8];
  const float* behp = (const float*)d_in[9];
  float* out = (float*)d_out;
  float* ws  = (float*)d_ws;

  hipMemsetAsync(d_ws, 0, 8192, stream);   // arrive flags + release + stats ring

  hipFuncSetAttribute((const void*)lngru13,
                      hipFuncAttributeMaxDynamicSharedMemorySize, LDS_BYTES);

  void* args[] = {(void*)&x, (void*)&h0, (void*)&Wx, (void*)&Wh, (void*)&bxp, (void*)&bhp,
                  (void*)&gxp, (void*)&bexp, (void*)&ghp, (void*)&behp, (void*)&out, (void*)&ws};
  hipLaunchCooperativeKernel((void*)lngru13, dim3(NBLK), dim3(NT), args, LDS_BYTES, stream);
}